// Round 20
// baseline (301.937 us; speedup 1.0000x reference)
//
#include <hip/hip_runtime.h>
#include <cstdint>
#include <cstddef>

#define N_NODES 8192
#define N_EDGES 131072
#define F_IN    512
#define H1C     32
#define H2C     16

// ---------------- helpers ----------------

__device__ __forceinline__ float block_reduce_sum(float v, int nthreads) {
    #pragma unroll
    for (int off = 32; off; off >>= 1) v += __shfl_down(v, off, 64);
    __shared__ float sred[16];
    int lane = threadIdx.x & 63, wid = threadIdx.x >> 6;
    if (lane == 0) sred[wid] = v;
    __syncthreads();
    float s = 0.0f;
    if (threadIdx.x == 0) {
        int nw = nthreads >> 6;
        for (int i = 0; i < nw; ++i) s += sred[i];
    }
    return s;
}

// POS_WEIGHT=10: y=1 -> 10*softplus(-l); y=0 -> softplus(l).
// Branch-free: sp(l) = lse + relu(l);  val = sp(l)*(1+9y) - 10*y*l
__device__ __forceinline__ float bce_elem(float l, int y) {
    float lse = __logf(1.0f + __expf(-fabsf(l)));
    float sp  = lse + fmaxf(l, 0.0f);
    float w   = (float)y;
    return fmaf(sp, fmaf(9.0f, w, 1.0f), -10.0f * w * l);
}

// ---------------- kernels ----------------

// zero cnt (32 KB) + done counter (f4 index 2048)
__global__ void k_init(float4* __restrict__ p) {
    int gid = blockIdx.x * 256 + threadIdx.x;
    float4 zz = {0.0f, 0.0f, 0.0f, 0.0f};
    if (gid <= 2048) p[gid] = zz;
}

// FUSED fill || gemm1: blocks 0-255 = gemm1 (W1 in LDS, barrier-free k-loop);
// blocks 256-767 = fixed-slot CSR fill (1 atomic pass), retire immediately.
// Independent work -> fill's atomic traffic hides under gemm1's FMA stream.
__global__ void __launch_bounds__(256)
k_fg(const int* __restrict__ src, const int* __restrict__ dst,
     int* __restrict__ cnt, int* __restrict__ csr_src,
     const float* __restrict__ x, const float* __restrict__ W1,
     float* __restrict__ h) {
    __shared__ float wsm[F_IN][H1C];   // 64 KB (gemm1 blocks only touch it)
    int tid = threadIdx.x, bid = blockIdx.x;

    if (bid >= 256) {
        int e = (bid - 256) * 256 + tid;
        int d = dst[e], sv = src[e];
        int slot = atomicAdd(&cnt[d], 1);
        if (slot < 64) csr_src[(d << 6) + slot] = sv;
        return;
    }

    {
        float4* wd = (float4*)wsm;
        const float4* wsrc = (const float4*)W1;
        #pragma unroll
        for (int i = 0; i < 16; ++i) wd[tid + i * 256] = wsrc[tid + i * 256];
    }
    __syncthreads();

    int row = (bid << 5) + (tid >> 3);
    int c4 = (tid & 7) << 2;
    const float4* xp = (const float4*)&x[(size_t)row * F_IN];

    float ax = 0.f, ay = 0.f, az = 0.f, aw = 0.f;
    #pragma unroll 8
    for (int k4 = 0; k4 < F_IN / 4; ++k4) {
        float4 xv = xp[k4];
        float4 w0 = *(const float4*)&wsm[k4 * 4 + 0][c4];
        float4 w1 = *(const float4*)&wsm[k4 * 4 + 1][c4];
        float4 w2 = *(const float4*)&wsm[k4 * 4 + 2][c4];
        float4 w3 = *(const float4*)&wsm[k4 * 4 + 3][c4];
        ax = fmaf(xv.x, w0.x, ax); ay = fmaf(xv.x, w0.y, ay);
        az = fmaf(xv.x, w0.z, az); aw = fmaf(xv.x, w0.w, aw);
        ax = fmaf(xv.y, w1.x, ax); ay = fmaf(xv.y, w1.y, ay);
        az = fmaf(xv.y, w1.z, az); aw = fmaf(xv.y, w1.w, aw);
        ax = fmaf(xv.z, w2.x, ax); ay = fmaf(xv.z, w2.y, ay);
        az = fmaf(xv.z, w2.z, az); aw = fmaf(xv.z, w2.w, aw);
        ax = fmaf(xv.w, w3.x, ax); ay = fmaf(xv.w, w3.y, ay);
        az = fmaf(xv.w, w3.z, az); aw = fmaf(xv.w, w3.w, aw);
    }
    float4 v; v.x = ax; v.y = ay; v.z = az; v.w = aw;
    *(float4*)&h[(size_t)row * H1C + c4] = v;
}

// FUSED gather1 + gemm2: wave owns a dst row (fixed-slot CSR, degree = cnt)
__global__ void __launch_bounds__(256)
k_g1g2(const int* __restrict__ csr_src, const int* __restrict__ cnt,
       const float* __restrict__ h, const float* __restrict__ W2,
       const float* __restrict__ W3, float* __restrict__ h2mu,
       float* __restrict__ h2lv) {
    __shared__ float w2s[H1C * H2C], w3s[H1C * H2C];
    __shared__ float h1s[4][33];
    int tid = threadIdx.x;
    {
        w2s[tid] = W2[tid]; w2s[tid + 256] = W2[tid + 256];
        w3s[tid] = W3[tid]; w3s[tid + 256] = W3[tid + 256];
    }
    __syncthreads();

    int w = tid >> 6;
    int row = blockIdx.x * 4 + w;
    int lane = tid & 63;
    int f = lane & 31, half = lane >> 5;
    int n = min(cnt[row], 64);
    float acc = 0.0f;
    for (int sl = half; sl < n; sl += 2) {
        int s = csr_src[(row << 6) + sl];
        float c = rsqrtf((float)(cnt[s] + 1));
        acc = fmaf(h[(s << 5) + f], c, acc);
    }
    acc += __shfl_down(acc, 32, 64);
    if (half == 0) {
        float di = rsqrtf((float)(n + 1)), d2 = di * di;
        float a1 = acc * di;
        h1s[w][f] = fmaxf(fmaf(h[(row << 5) + f], d2, a1), 0.0f);
    }
    // wave-synchronous LDS write->read
    if (half == 0) {
        const float* wsrc = (f < 16) ? w2s : w3s;
        int col = f & 15;
        float o = 0.0f;
        #pragma unroll
        for (int k = 0; k < H1C; ++k) o = fmaf(h1s[w][k], wsrc[(k << 4) + col], o);
        if (f < 16) h2mu[(row << 4) + col] = o;
        else        h2lv[(row << 4) + col] = o;
    }
}

// FUSED gather2 + zmu (fixed-slot CSR)
__global__ void __launch_bounds__(256)
k_g2z(const int* __restrict__ csr_src, const int* __restrict__ cnt,
      const float* __restrict__ h2mu, const float* __restrict__ h2lv,
      const float* __restrict__ eps, float* __restrict__ zbuf,
      float* __restrict__ out, float* __restrict__ kldp) {
    int tid = threadIdx.x;
    int row = blockIdx.x * 4 + (tid >> 6);
    int lane = tid & 63;
    int f = lane & 31, half = lane >> 5;
    int ff = f & 15;
    const float* hsrc = (f < 16) ? h2mu : h2lv;
    int n = min(cnt[row], 64);
    float acc = 0.0f;
    for (int sl = half; sl < n; sl += 2) {
        int s = csr_src[(row << 6) + sl];
        float c = rsqrtf((float)(cnt[s] + 1));
        acc = fmaf(hsrc[(s << 4) + ff], c, acc);
    }
    acc += __shfl_down(acc, 32, 64);
    float di = rsqrtf((float)(n + 1)), d2 = di * di;
    float val = fmaf(hsrc[(row << 4) + ff], d2, acc * di);  // mu (f<16) or lv
    float other = __shfl_xor(val, 16, 64);                  // swap mu<->lv
    float kterm = 0.0f;
    if (half == 0 && f < 16) {
        float m = val, lv = other;
        float el = __expf(lv);
        float zv = fmaf(eps[(row << 4) + ff], el, m);
        zbuf[(row << 4) + ff] = zv;
        out[1 + (row << 4) + ff] = m;
        kterm = 1.0f + 2.0f * lv - m * m - el * el;
    }
    float bs = block_reduce_sum(kterm, 256);
    if (tid == 0) kldp[blockIdx.x] = bs;
}

// ---- BCE v5: r16 core + FUSED final reduction (last-block-done pattern;
// deterministic: the reduction reads fixed indices in fixed order whichever
// block performs it). Saves the separate single-block k_final node.
__global__ void __launch_bounds__(256)
k_bce(const float* __restrict__ z, const int* __restrict__ adj,
      float* __restrict__ part, const float* __restrict__ kldp,
      const float* __restrict__ norm, float* __restrict__ out,
      int* __restrict__ done) {
    __shared__ float zrT[16][32];      // [k][row], 2 KB
    int tid = threadIdx.x;
    int band = blockIdx.x & 15;
    int rblk = blockIdx.x >> 4;
    int col0 = (band << 9) + (tid << 1);   // 2 cols per thread
    int row0 = rblk << 5;

    if (tid < 128) {
        int r = tid >> 2, q = (tid & 3) << 2;
        float4 v = *(const float4*)&z[(size_t)(row0 + r) * H2C + q];
        zrT[q + 0][r] = v.x; zrT[q + 1][r] = v.y;
        zrT[q + 2][r] = v.z; zrT[q + 3][r] = v.w;
    }

    float zc[2][16];
    {
        const float4* zp = (const float4*)&z[(size_t)col0 * H2C];
        #pragma unroll
        for (int q = 0; q < 8; ++q) {
            float4 v = zp[q];
            int c = q >> 2, qq = (q & 3) << 2;
            zc[c][qq + 0] = v.x; zc[c][qq + 1] = v.y;
            zc[c][qq + 2] = v.z; zc[c][qq + 3] = v.w;
        }
    }
    __syncthreads();

    float lsum = 0.0f;
    #pragma unroll
    for (int step = 0; step < 8; ++step) {
        int r0 = step << 2;
        const int* ap = adj + (size_t)(row0 + r0) * N_NODES + col0;
        int2 y0 = *(const int2*)(ap);
        int2 y1 = *(const int2*)(ap + N_NODES);
        int2 y2 = *(const int2*)(ap + 2 * N_NODES);
        int2 y3 = *(const int2*)(ap + 3 * N_NODES);

        float a[4][2];
        #pragma unroll
        for (int r = 0; r < 4; ++r) { a[r][0] = 0.0f; a[r][1] = 0.0f; }
        #pragma unroll
        for (int k = 0; k < 16; ++k) {
            float4 zr4 = *(const float4*)&zrT[k][r0];   // LDS broadcast
            a[0][0] = fmaf(zr4.x, zc[0][k], a[0][0]);
            a[0][1] = fmaf(zr4.x, zc[1][k], a[0][1]);
            a[1][0] = fmaf(zr4.y, zc[0][k], a[1][0]);
            a[1][1] = fmaf(zr4.y, zc[1][k], a[1][1]);
            a[2][0] = fmaf(zr4.z, zc[0][k], a[2][0]);
            a[2][1] = fmaf(zr4.z, zc[1][k], a[2][1]);
            a[3][0] = fmaf(zr4.w, zc[0][k], a[3][0]);
            a[3][1] = fmaf(zr4.w, zc[1][k], a[3][1]);
        }
        lsum += bce_elem(a[0][0], y0.x) + bce_elem(a[0][1], y0.y);
        lsum += bce_elem(a[1][0], y1.x) + bce_elem(a[1][1], y1.y);
        lsum += bce_elem(a[2][0], y2.x) + bce_elem(a[2][1], y2.y);
        lsum += bce_elem(a[3][0], y3.x) + bce_elem(a[3][1], y3.y);
    }

    float bs = block_reduce_sum(lsum, 256);
    __shared__ int amlast;
    if (tid == 0) {
        part[blockIdx.x] = bs;
        __threadfence();                       // release part write
        amlast = (atomicAdd(done, 1) == 4095);
    }
    __syncthreads();
    if (amlast) {
        __threadfence();                       // acquire all part writes
        double s = 0.0, k = 0.0;
        for (int i = tid; i < 4096; i += 256) s += (double)part[i];
        for (int i = tid; i < 2048; i += 256) k += (double)kldp[i];
        #pragma unroll
        for (int off = 32; off; off >>= 1) {
            s += __shfl_down(s, off, 64);
            k += __shfl_down(k, off, 64);
        }
        __shared__ double ss[4], kk[4];
        int lane = tid & 63, wid = tid >> 6;
        if (lane == 0) { ss[wid] = s; kk[wid] = k; }
        __syncthreads();
        if (tid == 0) {
            double st = ss[0] + ss[1] + ss[2] + ss[3];
            double kt = kk[0] + kk[1] + kk[2] + kk[3];
            double bce = st / ((double)N_NODES * (double)N_NODES);
            double kld = (-0.5 / (double)N_NODES) * (kt / (double)N_NODES);
            out[0] = (float)((double)norm[0] * bce + kld);
        }
    }
}

// ---------------- launch ----------------

extern "C" void kernel_launch(void* const* d_in, const int* in_sizes, int n_in,
                              void* d_out, int out_size, void* d_ws, size_t ws_size,
                              hipStream_t stream) {
    const float* x    = (const float*)d_in[0];
    const int*   ei   = (const int*)d_in[1];
    const int*   adj  = (const int*)d_in[2];
    const float* eps  = (const float*)d_in[3];
    const float* norm = (const float*)d_in[4];
    const float* W1   = (const float*)d_in[5];
    const float* W2   = (const float*)d_in[6];
    const float* W3   = (const float*)d_in[7];
    float* out = (float*)d_out;
    char*  ws  = (char*)d_ws;

    const int* src = ei;
    const int* dst = ei + N_EDGES;

    int*   cnt     = (int*)  (ws + 0);        // 32 KB
    int*   done    = (int*)  (ws + 32768);    // 16 B (zeroed by k_init)
    int*   csr_src = (int*)  (ws + 32832);    // 2 MB (8192 x 64)
    float* h       = (float*)(ws + 2129984);  // 1 MB
    float* h2mu    = (float*)(ws + 3178560);  // 512 KB
    float* h2lv    = (float*)(ws + 3702848);  // 512 KB
    float* zbuf    = (float*)(ws + 4227136);  // 512 KB
    float* part    = (float*)(ws + 4751424);  // 4096 f32
    float* kldp    = (float*)(ws + 4767808);  // 2048 f32

    k_init<<<9, 256, 0, stream>>>((float4*)cnt);
    k_fg<<<768, 256, 0, stream>>>(src, dst, cnt, csr_src, x, W1, h);
    k_g1g2<<<N_NODES / 4, 256, 0, stream>>>(csr_src, cnt, h, W2, W3, h2mu, h2lv);
    k_g2z<<<N_NODES / 4, 256, 0, stream>>>(csr_src, cnt, h2mu, h2lv, eps, zbuf, out, kldp);
    k_bce<<<4096, 256, 0, stream>>>(zbuf, adj, part, kldp, norm, out, done);
}

// Round 21
// 120.031 us; speedup vs baseline: 2.5155x; 2.5155x over previous
//
#include <hip/hip_runtime.h>
#include <cstdint>
#include <cstddef>

#define N_NODES 8192
#define N_EDGES 131072
#define F_IN    512
#define H1C     32
#define H2C     16

// ---------------- helpers ----------------

__device__ __forceinline__ float block_reduce_sum(float v, int nthreads) {
    #pragma unroll
    for (int off = 32; off; off >>= 1) v += __shfl_down(v, off, 64);
    __shared__ float sred[16];
    int lane = threadIdx.x & 63, wid = threadIdx.x >> 6;
    if (lane == 0) sred[wid] = v;
    __syncthreads();
    float s = 0.0f;
    if (threadIdx.x == 0) {
        int nw = nthreads >> 6;
        for (int i = 0; i < nw; ++i) s += sred[i];
    }
    return s;
}

// POS_WEIGHT=10: y=1 -> 10*softplus(-l); y=0 -> softplus(l).
// Branch-free: sp(l) = lse + relu(l);  val = sp(l)*(1+9y) - 10*y*l
__device__ __forceinline__ float bce_elem(float l, int y) {
    float lse = __logf(1.0f + __expf(-fabsf(l)));
    float sp  = lse + fmaxf(l, 0.0f);
    float w   = (float)y;
    return fmaf(sp, fmaf(9.0f, w, 1.0f), -10.0f * w * l);
}

// ---------------- kernels ----------------

// zero cnt (32 KB = 2048 float4)
__global__ void k_init(float4* __restrict__ p) {
    int gid = blockIdx.x * 256 + threadIdx.x;
    float4 zz = {0.0f, 0.0f, 0.0f, 0.0f};
    p[gid] = zz;
}

// FUSED fill || gemm1: blocks 0-255 = gemm1 (W1 in LDS, barrier-free k-loop);
// blocks 256-767 = fixed-slot CSR fill (1 atomic pass), retire immediately.
// Independent work -> fill's atomic traffic hides under gemm1's FMA stream.
// NOTE: NO device-scope fences anywhere (r20 lesson: __threadfence in a
// throughput kernel forces per-XCD L2 writebacks -> 5x slowdown).
__global__ void __launch_bounds__(256)
k_fg(const int* __restrict__ src, const int* __restrict__ dst,
     int* __restrict__ cnt, int* __restrict__ csr_src,
     const float* __restrict__ x, const float* __restrict__ W1,
     float* __restrict__ h) {
    __shared__ float wsm[F_IN][H1C];   // 64 KB (gemm1 blocks only touch it)
    int tid = threadIdx.x, bid = blockIdx.x;

    if (bid >= 256) {
        int e = (bid - 256) * 256 + tid;
        int d = dst[e], sv = src[e];
        int slot = atomicAdd(&cnt[d], 1);
        if (slot < 64) csr_src[(d << 6) + slot] = sv;
        return;
    }

    {
        float4* wd = (float4*)wsm;
        const float4* wsrc = (const float4*)W1;
        #pragma unroll
        for (int i = 0; i < 16; ++i) wd[tid + i * 256] = wsrc[tid + i * 256];
    }
    __syncthreads();

    int row = (bid << 5) + (tid >> 3);
    int c4 = (tid & 7) << 2;
    const float4* xp = (const float4*)&x[(size_t)row * F_IN];

    float ax = 0.f, ay = 0.f, az = 0.f, aw = 0.f;
    #pragma unroll 8
    for (int k4 = 0; k4 < F_IN / 4; ++k4) {
        float4 xv = xp[k4];
        float4 w0 = *(const float4*)&wsm[k4 * 4 + 0][c4];
        float4 w1 = *(const float4*)&wsm[k4 * 4 + 1][c4];
        float4 w2 = *(const float4*)&wsm[k4 * 4 + 2][c4];
        float4 w3 = *(const float4*)&wsm[k4 * 4 + 3][c4];
        ax = fmaf(xv.x, w0.x, ax); ay = fmaf(xv.x, w0.y, ay);
        az = fmaf(xv.x, w0.z, az); aw = fmaf(xv.x, w0.w, aw);
        ax = fmaf(xv.y, w1.x, ax); ay = fmaf(xv.y, w1.y, ay);
        az = fmaf(xv.y, w1.z, az); aw = fmaf(xv.y, w1.w, aw);
        ax = fmaf(xv.z, w2.x, ax); ay = fmaf(xv.z, w2.y, ay);
        az = fmaf(xv.z, w2.z, az); aw = fmaf(xv.z, w2.w, aw);
        ax = fmaf(xv.w, w3.x, ax); ay = fmaf(xv.w, w3.y, ay);
        az = fmaf(xv.w, w3.z, az); aw = fmaf(xv.w, w3.w, aw);
    }
    float4 v; v.x = ax; v.y = ay; v.z = az; v.w = aw;
    *(float4*)&h[(size_t)row * H1C + c4] = v;
}

// FUSED gather1 + gemm2: wave owns a dst row (fixed-slot CSR, degree = cnt)
__global__ void __launch_bounds__(256)
k_g1g2(const int* __restrict__ csr_src, const int* __restrict__ cnt,
       const float* __restrict__ h, const float* __restrict__ W2,
       const float* __restrict__ W3, float* __restrict__ h2mu,
       float* __restrict__ h2lv) {
    __shared__ float w2s[H1C * H2C], w3s[H1C * H2C];
    __shared__ float h1s[4][33];
    int tid = threadIdx.x;
    {
        w2s[tid] = W2[tid]; w2s[tid + 256] = W2[tid + 256];
        w3s[tid] = W3[tid]; w3s[tid + 256] = W3[tid + 256];
    }
    __syncthreads();

    int w = tid >> 6;
    int row = blockIdx.x * 4 + w;
    int lane = tid & 63;
    int f = lane & 31, half = lane >> 5;
    int n = min(cnt[row], 64);
    float acc = 0.0f;
    for (int sl = half; sl < n; sl += 2) {
        int s = csr_src[(row << 6) + sl];
        float c = rsqrtf((float)(cnt[s] + 1));
        acc = fmaf(h[(s << 5) + f], c, acc);
    }
    acc += __shfl_down(acc, 32, 64);
    if (half == 0) {
        float di = rsqrtf((float)(n + 1)), d2 = di * di;
        float a1 = acc * di;
        h1s[w][f] = fmaxf(fmaf(h[(row << 5) + f], d2, a1), 0.0f);
    }
    // wave-synchronous LDS write->read
    if (half == 0) {
        const float* wsrc = (f < 16) ? w2s : w3s;
        int col = f & 15;
        float o = 0.0f;
        #pragma unroll
        for (int k = 0; k < H1C; ++k) o = fmaf(h1s[w][k], wsrc[(k << 4) + col], o);
        if (f < 16) h2mu[(row << 4) + col] = o;
        else        h2lv[(row << 4) + col] = o;
    }
}

// FUSED gather2 + zmu (fixed-slot CSR)
__global__ void __launch_bounds__(256)
k_g2z(const int* __restrict__ csr_src, const int* __restrict__ cnt,
      const float* __restrict__ h2mu, const float* __restrict__ h2lv,
      const float* __restrict__ eps, float* __restrict__ zbuf,
      float* __restrict__ out, float* __restrict__ kldp) {
    int tid = threadIdx.x;
    int row = blockIdx.x * 4 + (tid >> 6);
    int lane = tid & 63;
    int f = lane & 31, half = lane >> 5;
    int ff = f & 15;
    const float* hsrc = (f < 16) ? h2mu : h2lv;
    int n = min(cnt[row], 64);
    float acc = 0.0f;
    for (int sl = half; sl < n; sl += 2) {
        int s = csr_src[(row << 6) + sl];
        float c = rsqrtf((float)(cnt[s] + 1));
        acc = fmaf(hsrc[(s << 4) + ff], c, acc);
    }
    acc += __shfl_down(acc, 32, 64);
    float di = rsqrtf((float)(n + 1)), d2 = di * di;
    float val = fmaf(hsrc[(row << 4) + ff], d2, acc * di);  // mu (f<16) or lv
    float other = __shfl_xor(val, 16, 64);                  // swap mu<->lv
    float kterm = 0.0f;
    if (half == 0 && f < 16) {
        float m = val, lv = other;
        float el = __expf(lv);
        float zv = fmaf(eps[(row << 4) + ff], el, m);
        zbuf[(row << 4) + ff] = zv;
        out[1 + (row << 4) + ff] = m;
        kterm = 1.0f + 2.0f * lv - m * m - el * el;
    }
    float bs = block_reduce_sum(kterm, 256);
    if (tid == 0) kldp[blockIdx.x] = bs;
}

// ---- BCE v4 (identical to round 16/19 — no fences, no done counter) ----
__global__ void __launch_bounds__(256)
k_bce(const float* __restrict__ z, const int* __restrict__ adj,
      float* __restrict__ part) {
    __shared__ float zrT[16][32];      // [k][row], 2 KB
    int tid = threadIdx.x;
    int band = blockIdx.x & 15;
    int rblk = blockIdx.x >> 4;
    int col0 = (band << 9) + (tid << 1);   // 2 cols per thread
    int row0 = rblk << 5;

    if (tid < 128) {
        int r = tid >> 2, q = (tid & 3) << 2;
        float4 v = *(const float4*)&z[(size_t)(row0 + r) * H2C + q];
        zrT[q + 0][r] = v.x; zrT[q + 1][r] = v.y;
        zrT[q + 2][r] = v.z; zrT[q + 3][r] = v.w;
    }

    float zc[2][16];
    {
        const float4* zp = (const float4*)&z[(size_t)col0 * H2C];
        #pragma unroll
        for (int q = 0; q < 8; ++q) {
            float4 v = zp[q];
            int c = q >> 2, qq = (q & 3) << 2;
            zc[c][qq + 0] = v.x; zc[c][qq + 1] = v.y;
            zc[c][qq + 2] = v.z; zc[c][qq + 3] = v.w;
        }
    }
    __syncthreads();

    float lsum = 0.0f;
    #pragma unroll
    for (int step = 0; step < 8; ++step) {
        int r0 = step << 2;
        const int* ap = adj + (size_t)(row0 + r0) * N_NODES + col0;
        int2 y0 = *(const int2*)(ap);
        int2 y1 = *(const int2*)(ap + N_NODES);
        int2 y2 = *(const int2*)(ap + 2 * N_NODES);
        int2 y3 = *(const int2*)(ap + 3 * N_NODES);

        float a[4][2];
        #pragma unroll
        for (int r = 0; r < 4; ++r) { a[r][0] = 0.0f; a[r][1] = 0.0f; }
        #pragma unroll
        for (int k = 0; k < 16; ++k) {
            float4 zr4 = *(const float4*)&zrT[k][r0];   // LDS broadcast
            a[0][0] = fmaf(zr4.x, zc[0][k], a[0][0]);
            a[0][1] = fmaf(zr4.x, zc[1][k], a[0][1]);
            a[1][0] = fmaf(zr4.y, zc[0][k], a[1][0]);
            a[1][1] = fmaf(zr4.y, zc[1][k], a[1][1]);
            a[2][0] = fmaf(zr4.z, zc[0][k], a[2][0]);
            a[2][1] = fmaf(zr4.z, zc[1][k], a[2][1]);
            a[3][0] = fmaf(zr4.w, zc[0][k], a[3][0]);
            a[3][1] = fmaf(zr4.w, zc[1][k], a[3][1]);
        }
        lsum += bce_elem(a[0][0], y0.x) + bce_elem(a[0][1], y0.y);
        lsum += bce_elem(a[1][0], y1.x) + bce_elem(a[1][1], y1.y);
        lsum += bce_elem(a[2][0], y2.x) + bce_elem(a[2][1], y2.y);
        lsum += bce_elem(a[3][0], y3.x) + bce_elem(a[3][1], y3.y);
    }

    float bs = block_reduce_sum(lsum, 256);
    if (tid == 0) part[blockIdx.x] = bs;
}

__global__ void k_final(const float* __restrict__ part, const float* __restrict__ kldp,
                        const float* __restrict__ norm, float* __restrict__ out) {
    double s = 0.0, k = 0.0;
    for (int i = threadIdx.x; i < 4096; i += 256) s += (double)part[i];
    for (int i = threadIdx.x; i < 2048; i += 256) k += (double)kldp[i];
    #pragma unroll
    for (int off = 32; off; off >>= 1) {
        s += __shfl_down(s, off, 64);
        k += __shfl_down(k, off, 64);
    }
    __shared__ double ss[4], kk[4];
    int lane = threadIdx.x & 63, wid = threadIdx.x >> 6;
    if (lane == 0) { ss[wid] = s; kk[wid] = k; }
    __syncthreads();
    if (threadIdx.x == 0) {
        double st = ss[0] + ss[1] + ss[2] + ss[3];
        double kt = kk[0] + kk[1] + kk[2] + kk[3];
        double bce = st / ((double)N_NODES * (double)N_NODES);
        double kld = (-0.5 / (double)N_NODES) * (kt / (double)N_NODES);
        out[0] = (float)((double)norm[0] * bce + kld);
    }
}

// ---------------- launch ----------------

extern "C" void kernel_launch(void* const* d_in, const int* in_sizes, int n_in,
                              void* d_out, int out_size, void* d_ws, size_t ws_size,
                              hipStream_t stream) {
    const float* x    = (const float*)d_in[0];
    const int*   ei   = (const int*)d_in[1];
    const int*   adj  = (const int*)d_in[2];
    const float* eps  = (const float*)d_in[3];
    const float* norm = (const float*)d_in[4];
    const float* W1   = (const float*)d_in[5];
    const float* W2   = (const float*)d_in[6];
    const float* W3   = (const float*)d_in[7];
    float* out = (float*)d_out;
    char*  ws  = (char*)d_ws;

    const int* src = ei;
    const int* dst = ei + N_EDGES;

    int*   cnt     = (int*)  (ws + 0);        // 32 KB
    int*   csr_src = (int*)  (ws + 32768);    // 2 MB (8192 x 64)
    float* h       = (float*)(ws + 2129920);  // 1 MB
    float* h2mu    = (float*)(ws + 3178496);  // 512 KB
    float* h2lv    = (float*)(ws + 3702784);  // 512 KB
    float* zbuf    = (float*)(ws + 4227072);  // 512 KB
    float* part    = (float*)(ws + 4751360);  // 4096 f32
    float* kldp    = (float*)(ws + 4767744);  // 2048 f32

    k_init<<<8, 256, 0, stream>>>((float4*)cnt);
    k_fg<<<768, 256, 0, stream>>>(src, dst, cnt, csr_src, x, W1, h);
    k_g1g2<<<N_NODES / 4, 256, 0, stream>>>(csr_src, cnt, h, W2, W3, h2mu, h2lv);
    k_g2z<<<N_NODES / 4, 256, 0, stream>>>(csr_src, cnt, h2mu, h2lv, eps, zbuf, out, kldp);
    k_bce<<<4096, 256, 0, stream>>>(zbuf, adj, part);
    k_final<<<1, 256, 0, stream>>>(part, kldp, norm, out);
}